// Round 1
// 43072.781 us; speedup vs baseline: 1.4650x; 1.4650x over previous
//
#include <hip/hip_runtime.h>
#include <cstdint>
#include <cstddef>

typedef __attribute__((ext_vector_type(8))) __bf16 bhalf8;
typedef __attribute__((ext_vector_type(4))) float floatx4;

#define B_ 32
#define T_ 2048
#define CTR_STRIDE 32   // dwords between barrier counters (128 B)

__device__ __forceinline__ float sigm_f(float x){ return 1.0f / (1.0f + __expf(-x)); }
__device__ __forceinline__ float tanh_f(float x){ return 1.0f - 2.0f / (1.0f + __expf(2.0f*x)); }

// ---------------- init: zero barrier counters (4 layers x 8 counters x 32-dword stride) ----
__global__ void k_init(unsigned* bars){
  int i = blockIdx.x * 256 + threadIdx.x;
  if (i < 4 * 8 * CTR_STRIDE) bars[i] = 0u;
}

// ---------------- fp32 -> bf16 convert ----------------
__global__ void k_cvt(const float* __restrict__ s, __bf16* __restrict__ d, int n){
  int i = blockIdx.x * 256 + threadIdx.x;
  if (i < n) d[i] = (__bf16)s[i];
}

// ---------------- per-b transpose: in [R][C] -> out [C][R] ----------------
template<typename TI, typename TO>
__global__ void k_transpose(const TI* __restrict__ in, TO* __restrict__ out, int R, int C){
  __shared__ float tile[32][33];
  const size_t bo = (size_t)blockIdx.z * (size_t)R * (size_t)C;
  const int c0 = blockIdx.x * 32, r0 = blockIdx.y * 32;
  const int tx = threadIdx.x, ty = threadIdx.y;
#pragma unroll
  for (int k2 = 0; k2 < 4; ++k2)
    tile[ty + k2*8][tx] = (float)in[bo + (size_t)(r0 + ty + k2*8) * C + c0 + tx];
  __syncthreads();
#pragma unroll
  for (int k2 = 0; k2 < 4; ++k2)
    out[bo + (size_t)(c0 + ty + k2*8) * R + r0 + tx] = (TO)tile[tx][ty + k2*8];
}

// ---------------- GEMM: C[M,N] = A[M,K] * W[N,K]^T + bias, all bf16 in, bf16 out ----
__global__ __launch_bounds__(256) void k_gemm(
    const __bf16* __restrict__ A, const __bf16* __restrict__ W,
    const float* __restrict__ bias, __bf16* __restrict__ C,
    int M, int N, int K)
{
  const int tid = threadIdx.x, wave = tid >> 6, lane = tid & 63;
  const int quad = lane >> 4, l = lane & 15;
  const int wy = wave >> 1, wx = wave & 1;
  const size_t rA = (size_t)blockIdx.y * 128 + (size_t)wy * 64;
  const size_t rW = (size_t)blockIdx.x * 128 + (size_t)wx * 64;
  floatx4 acc[4][4] = {};
  for (int k0 = 0; k0 < K; k0 += 32){
    bhalf8 af[4], wf[4];
#pragma unroll
    for (int i = 0; i < 4; ++i)
      af[i] = *(const bhalf8*)(A + (rA + 16*i + l) * (size_t)K + k0 + quad*8);
#pragma unroll
    for (int j = 0; j < 4; ++j)
      wf[j] = *(const bhalf8*)(W + (rW + 16*j + l) * (size_t)K + k0 + quad*8);
#pragma unroll
    for (int i = 0; i < 4; ++i)
#pragma unroll
      for (int j = 0; j < 4; ++j)
        acc[i][j] = __builtin_amdgcn_mfma_f32_16x16x32_bf16(af[i], wf[j], acc[i][j], 0, 0, 0);
  }
#pragma unroll
  for (int j = 0; j < 4; ++j){
    const float bv = bias[rW + 16*j + l];
#pragma unroll
    for (int i = 0; i < 4; ++i)
#pragma unroll
      for (int r = 0; r < 4; ++r)
        C[(rA + 16*i + quad*4 + r) * (size_t)N + rW + 16*j + l] = (__bf16)(acc[i][j][r] + bv);
  }
}

// ---------------- grid barrier: 8 counters 128B apart, write-through publication ------
// No release fence (no buffer_wbl2): h is published via sc1 write-through atomic stores,
// drained by the vmcnt(0) inside __syncthreads() before the counter increment.
__device__ __forceinline__ void grid_barrier8(unsigned* bars, int my_ctr, unsigned per_target){
  __syncthreads();   // drains this block's vmem stores (incl. write-through h stores)
  if (threadIdx.x < 8){
    if ((int)threadIdx.x == my_ctr)
      __hip_atomic_fetch_add(bars + my_ctr * CTR_STRIDE, 1u,
                             __ATOMIC_RELAXED, __HIP_MEMORY_SCOPE_AGENT);
    while (__hip_atomic_load(bars + threadIdx.x * CTR_STRIDE,
                             __ATOMIC_RELAXED, __HIP_MEMORY_SCOPE_AGENT) < per_target)
      __builtin_amdgcn_s_sleep(1);
  }
  __syncthreads();
}

// agent-coherent 16B load (bypasses possibly-stale per-XCD L2)
__device__ __forceinline__ bhalf8 load_coherent16(const __bf16* p){
  union { unsigned long long q[2]; bhalf8 v; } u;
  u.q[0] = __hip_atomic_load((const unsigned long long*)p,     __ATOMIC_RELAXED, __HIP_MEMORY_SCOPE_AGENT);
  u.q[1] = __hip_atomic_load((const unsigned long long*)p + 1, __ATOMIC_RELAXED, __HIP_MEMORY_SCOPE_AGENT);
  return u.v;
}

// ---------------- persistent GRU scan ----------------
// grid = H/16 blocks; block owns units [u0, u0+16) where u0 is XCD-swizzled so each XCD
// owns whole 128-B lines of h and Y rows. 4 waves = (mtile m) x (K-half kh).
// Weights stay in L2 (plain loads). h double-buffered bf16 in global: written via
// write-through relaxed agent atomic dword stores, read via sc1 coherent loads.
// Block-private fp32 h in LDS for the z*h term.
template<int H>
__global__ __launch_bounds__(256) void k_scan(
    const __bf16* __restrict__ xg,   // [B*T][3H] bf16 (b_ih already added)
    const __bf16* __restrict__ whh,  // [3H][H] bf16
    const float*  __restrict__ bhh,  // [3H]
    __bf16* __restrict__ hb0, __bf16* __restrict__ hb1,  // [B][H] double buffer
    __bf16* __restrict__ Y,          // [B*T][H]
    unsigned* __restrict__ bar)      // 8 counters, CTR_STRIDE apart
{
  __shared__ float part[2*3*2*16*17];  // [kh][gate][m][row16][col16 pad17]
  __shared__ float hown[32*17];        // private fp32 h for this block's units
  const int tid = threadIdx.x, wave = tid >> 6, lane = tid & 63;
  const int quad = lane >> 4, l = lane & 15;
  const int m = wave & 1, kh = wave >> 1;
  const unsigned nblk = gridDim.x;
  const int bid = blockIdx.x;
  const int my_ctr = bid & 7;
  // XCD swizzle: blocks {x, x+8, x+16, ...} (round-robin XCD x) get contiguous units
  const int swz = (bid & 7) * ((int)nblk >> 3) + (bid >> 3);
  const int u0 = swz * 16;
  const unsigned per_blk = nblk >> 3;   // adds per counter per epoch

  for (int i = tid; i < 32*16; i += 256){
    int b = i >> 4, u = i & 15;
    hown[b*17 + u] = 0.0f;
  }
  // publish h0 = 0 write-through (read by other blocks at t=0)
  for (int i = tid; i < 32*8; i += 256){
    int b = i >> 3, d = i & 7;
    __hip_atomic_store((unsigned*)(hb0 + (size_t)b*H + u0) + d, 0u,
                       __ATOMIC_RELAXED, __HIP_MEMORY_SCOPE_AGENT);
  }
  const float bh0 = bhh[0*H + u0 + l];
  const float bh1 = bhh[1*H + u0 + l];
  const float bh2 = bhh[2*H + u0 + l];
  const __bf16* wr0 = whh + (size_t)(0*H + u0 + l)*H + kh*(H/2);
  const __bf16* wr1 = whh + (size_t)(1*H + u0 + l)*H + kh*(H/2);
  const __bf16* wr2 = whh + (size_t)(2*H + u0 + l)*H + kh*(H/2);
  const __bf16* ar0 = hb0 + (size_t)(16*m + l)*H + kh*(H/2);
  const __bf16* ar1 = hb1 + (size_t)(16*m + l)*H + kh*(H/2);
  const int b0g = 16*m + quad*4 + 2*kh;   // gating batch-row base (C-layout rows)

  auto xgi = [&](int b, int t, int g)->size_t {
    return ((size_t)b*T_ + t)*(size_t)(3*H) + (size_t)g*H + u0 + l;
  };

  __bf16 xq[3][2];
#pragma unroll
  for (int g = 0; g < 3; ++g)
#pragma unroll
    for (int r2 = 0; r2 < 2; ++r2)
      xq[g][r2] = xg[xgi(b0g + r2, 0, g)];

  grid_barrier8(bar, my_ctr, per_blk);   // epoch 1: h0 zeros visible everywhere

  for (int t = 0; t < T_; ++t){
    const __bf16* ar = (t & 1) ? ar1 : ar0;
    __bf16* hd = (t & 1) ? hb0 : hb1;
    floatx4 a0 = {0.f,0.f,0.f,0.f}, a1 = a0, a2 = a0;
#pragma unroll
    for (int ks = 0; ks < H/64; ++ks){
      bhalf8 av = load_coherent16(ar + ks*32 + quad*8);
      bhalf8 w0 = *(const bhalf8*)(wr0 + ks*32 + quad*8);
      bhalf8 w1 = *(const bhalf8*)(wr1 + ks*32 + quad*8);
      bhalf8 w2 = *(const bhalf8*)(wr2 + ks*32 + quad*8);
      a0 = __builtin_amdgcn_mfma_f32_16x16x32_bf16(av, w0, a0, 0, 0, 0);
      a1 = __builtin_amdgcn_mfma_f32_16x16x32_bf16(av, w1, a1, 0, 0, 0);
      a2 = __builtin_amdgcn_mfma_f32_16x16x32_bf16(av, w2, a2, 0, 0, 0);
    }
    // stash partials: slot base ((kh*3+g)*2+m)*272
    const int sb = (kh*6 + m)*272;
#pragma unroll
    for (int r = 0; r < 4; ++r){
      part[sb +        (quad*4+r)*17 + l] = a0[r];
      part[sb + 544  + (quad*4+r)*17 + l] = a1[r];
      part[sb + 1088 + (quad*4+r)*17 + l] = a2[r];
    }
    __syncthreads();
    // gating: wave (m,kh) handles rows quad*4 + 2*kh + {0,1}
#pragma unroll
    for (int r2 = 0; r2 < 2; ++r2){
      const int row = quad*4 + 2*kh + r2;
      const int bb  = 16*m + row;
      const float hr = part[(0+m)*272 + row*17 + l] + part[(6+m)*272  + row*17 + l] + bh0;
      const float hz = part[(2+m)*272 + row*17 + l] + part[(8+m)*272  + row*17 + l] + bh1;
      const float hn = part[(4+m)*272 + row*17 + l] + part[(10+m)*272 + row*17 + l] + bh2;
      const float xr = (float)xq[0][r2], xz = (float)xq[1][r2], xn = (float)xq[2][r2];
      const float rg = sigm_f(xr + hr);
      const float zg = sigm_f(xz + hz);
      const float ng = tanh_f(xn + rg*hn);
      const float hp = hown[bb*17 + l];
      const float hnew = (1.0f - zg)*ng + zg*hp;
      hown[bb*17 + l] = hnew;
      // pack 2 adjacent units (lane l even gets partner l+1 via shfl) -> dword stores
      const __bf16 hb16 = (__bf16)hnew;
      const unsigned mybits = (unsigned)__builtin_bit_cast(unsigned short, hb16);
      const unsigned other  = (unsigned)__shfl_xor((int)mybits, 1);
      if ((l & 1) == 0){
        const unsigned packed = mybits | (other << 16);
        // write-through publication of h (device-coherent, no fence needed)
        __hip_atomic_store((unsigned*)(hd + (size_t)bb*H + u0 + l), packed,
                           __ATOMIC_RELAXED, __HIP_MEMORY_SCOPE_AGENT);
        // Y is only read by a later kernel: nontemporal, lazy writeback
        __builtin_nontemporal_store(packed, (unsigned*)(Y + ((size_t)bb*T_ + t)*H + u0 + l));
      }
    }
    if (t + 1 < T_){
      // prefetch next step's xg before the barrier (hides HBM latency)
#pragma unroll
      for (int g = 0; g < 3; ++g)
#pragma unroll
        for (int r2 = 0; r2 < 2; ++r2)
          xq[g][r2] = xg[xgi(b0g + r2, t + 1, g)];
      grid_barrier8(bar, my_ctr, per_blk * (unsigned)(t + 2));
    }
  }
}

// ---------------- launch ----------------
extern "C" void kernel_launch(void* const* d_in, const int* in_sizes, int n_in,
                              void* d_out, int out_size, void* d_ws, size_t ws_size,
                              hipStream_t stream) {
  (void)in_sizes; (void)n_in; (void)out_size; (void)ws_size;
  const float* x = (const float*)d_in[0];
  const float* wih[4] = {(const float*)d_in[1], (const float*)d_in[5], (const float*)d_in[9],  (const float*)d_in[13]};
  const float* whh[4] = {(const float*)d_in[2], (const float*)d_in[6], (const float*)d_in[10], (const float*)d_in[14]};
  const float* bih[4] = {(const float*)d_in[3], (const float*)d_in[7], (const float*)d_in[11], (const float*)d_in[15]};
  const float* bhh[4] = {(const float*)d_in[4], (const float*)d_in[8], (const float*)d_in[12], (const float*)d_in[16]};
  float* out = (float*)d_out;

  char* ws = (char*)d_ws;
  size_t off = 0;
  auto take = [&](size_t bytes)->char* {
    char* p = ws + off; off = (off + bytes + 255) & ~(size_t)255; return p;
  };
  const int IN[4] = {256, 512, 512, 1024};
  const int HH[4] = {512, 512, 1024, 1024};

  unsigned* bars = (unsigned*)take((size_t)4 * 8 * CTR_STRIDE * sizeof(unsigned));
  __bf16* wihb[4]; __bf16* whhb[4];
  for (int i = 0; i < 4; ++i){
    wihb[i] = (__bf16*)take((size_t)3*HH[i]*IN[i]*2);
    whhb[i] = (__bf16*)take((size_t)3*HH[i]*HH[i]*2);
  }
  __bf16* XG  = (__bf16*)take((size_t)B_*T_*3*1024*2);   // 402 MB
  __bf16* Ya  = (__bf16*)take((size_t)B_*T_*1024*2);     // 134 MB
  __bf16* Yb  = (__bf16*)take((size_t)B_*T_*1024*2);     // 134 MB
  __bf16* hba = (__bf16*)take((size_t)B_*1024*2);
  __bf16* hbb = (__bf16*)take((size_t)B_*1024*2);
  __bf16* X0  = Yb;  // alias: X0 dead before Yb is first written (layer-1 scan)

  k_init<<<4, 256, 0, stream>>>(bars);
  for (int i = 0; i < 4; ++i){
    const int nih = 3*HH[i]*IN[i], nhh = 3*HH[i]*HH[i];
    k_cvt<<<(nih + 255)/256, 256, 0, stream>>>(wih[i], wihb[i], nih);
    k_cvt<<<(nhh + 255)/256, 256, 0, stream>>>(whh[i], whhb[i], nhh);
  }
  // x [B][256][T] -> X0 [B][T][256] bf16
  k_transpose<float, __bf16><<<dim3(T_/32, 256/32, B_), dim3(32, 8), 0, stream>>>(x, X0, 256, T_);

  const int M = B_ * T_;
  // layer 00: 256 -> 512
  k_gemm<<<dim3(1536/128, M/128), 256, 0, stream>>>(X0, wihb[0], bih[0], XG, M, 1536, 256);
  k_scan<512><<<32, 256, 0, stream>>>(XG, whhb[0], bhh[0], hba, hbb, Ya, bars + 0*8*CTR_STRIDE);
  // layer 01: 512 -> 512
  k_gemm<<<dim3(1536/128, M/128), 256, 0, stream>>>(Ya, wihb[1], bih[1], XG, M, 1536, 512);
  k_scan<512><<<32, 256, 0, stream>>>(XG, whhb[1], bhh[1], hba, hbb, Yb, bars + 1*8*CTR_STRIDE);
  // layer 10: 512 -> 1024
  k_gemm<<<dim3(3072/128, M/128), 256, 0, stream>>>(Yb, wihb[2], bih[2], XG, M, 3072, 512);
  k_scan<1024><<<64, 256, 0, stream>>>(XG, whhb[2], bhh[2], hba, hbb, Ya, bars + 2*8*CTR_STRIDE);
  // layer 11: 1024 -> 1024
  k_gemm<<<dim3(3072/128, M/128), 256, 0, stream>>>(Ya, wihb[3], bih[3], XG, M, 3072, 1024);
  k_scan<1024><<<64, 256, 0, stream>>>(XG, whhb[3], bhh[3], hba, hbb, Yb, bars + 3*8*CTR_STRIDE);
  // Yb [B][T][1024] -> out [B][1024][T] fp32
  k_transpose<__bf16, float><<<dim3(1024/32, T_/32, B_), dim3(32, 8), 0, stream>>>(Yb, out, T_, 1024);
}

// Round 2
// 40718.051 us; speedup vs baseline: 1.5498x; 1.0578x over previous
//
#include <hip/hip_runtime.h>
#include <cstdint>
#include <cstddef>

typedef __attribute__((ext_vector_type(8))) __bf16 bhalf8;
typedef __attribute__((ext_vector_type(4))) float floatx4;

#define B_ 32
#define T_ 2048
#define CTR_STRIDE 32   // dwords between barrier counters (128 B)
#define NCTR 16
#define NBLK 192        // 32 (L0) + 32 (L1) + 64 (L2) + 64 (L3)

__device__ __forceinline__ float sigm_f(float x){ return 1.0f / (1.0f + __expf(-x)); }
__device__ __forceinline__ float tanh_f(float x){ return 1.0f - 2.0f / (1.0f + __expf(2.0f*x)); }

// ---------------- init: zero barrier counters ----------------
__global__ void k_init(unsigned* bars){
  int i = blockIdx.x * 256 + threadIdx.x;
  if (i < NCTR * CTR_STRIDE) bars[i] = 0u;
}

// ---------------- fp32 -> bf16 convert ----------------
__global__ void k_cvt(const float* __restrict__ s, __bf16* __restrict__ d, int n){
  int i = blockIdx.x * 256 + threadIdx.x;
  if (i < n) d[i] = (__bf16)s[i];
}

// ---------------- fp32 [R][C] -> bf16 packed into [R][dstride] at col doff ----------
__global__ void k_pack(const float* __restrict__ s, __bf16* __restrict__ d,
                       int R, int C, int dstride, int doff){
  int i = blockIdx.x * 256 + threadIdx.x;
  if (i < R * C){
    int r = i / C, c = i - r * C;
    d[(size_t)r * dstride + doff + c] = (__bf16)s[i];
  }
}

// ---------------- per-b transpose: in [R][C] -> out [C][R] ----------------
template<typename TI, typename TO>
__global__ void k_transpose(const TI* __restrict__ in, TO* __restrict__ out, int R, int C){
  __shared__ float tile[32][33];
  const size_t bo = (size_t)blockIdx.z * (size_t)R * (size_t)C;
  const int c0 = blockIdx.x * 32, r0 = blockIdx.y * 32;
  const int tx = threadIdx.x, ty = threadIdx.y;
#pragma unroll
  for (int k2 = 0; k2 < 4; ++k2)
    tile[ty + k2*8][tx] = (float)in[bo + (size_t)(r0 + ty + k2*8) * C + c0 + tx];
  __syncthreads();
#pragma unroll
  for (int k2 = 0; k2 < 4; ++k2)
    out[bo + (size_t)(c0 + ty + k2*8) * R + r0 + tx] = (TO)tile[tx][ty + k2*8];
}

// ---------------- GEMM: C[M,N] = A[M,K] * W[N,K]^T + bias, bf16 in, bf16 out ----
__global__ __launch_bounds__(256) void k_gemm(
    const __bf16* __restrict__ A, const __bf16* __restrict__ W,
    const float* __restrict__ bias, __bf16* __restrict__ C,
    int M, int N, int K)
{
  const int tid = threadIdx.x, wave = tid >> 6, lane = tid & 63;
  const int quad = lane >> 4, l = lane & 15;
  const int wy = wave >> 1, wx = wave & 1;
  const size_t rA = (size_t)blockIdx.y * 128 + (size_t)wy * 64;
  const size_t rW = (size_t)blockIdx.x * 128 + (size_t)wx * 64;
  floatx4 acc[4][4] = {};
  for (int k0 = 0; k0 < K; k0 += 32){
    bhalf8 af[4], wf[4];
#pragma unroll
    for (int i = 0; i < 4; ++i)
      af[i] = *(const bhalf8*)(A + (rA + 16*i + l) * (size_t)K + k0 + quad*8);
#pragma unroll
    for (int j = 0; j < 4; ++j)
      wf[j] = *(const bhalf8*)(W + (rW + 16*j + l) * (size_t)K + k0 + quad*8);
#pragma unroll
    for (int i = 0; i < 4; ++i)
#pragma unroll
      for (int j = 0; j < 4; ++j)
        acc[i][j] = __builtin_amdgcn_mfma_f32_16x16x32_bf16(af[i], wf[j], acc[i][j], 0, 0, 0);
  }
#pragma unroll
  for (int j = 0; j < 4; ++j){
    const float bv = bias[rW + 16*j + l];
#pragma unroll
    for (int i = 0; i < 4; ++i)
#pragma unroll
      for (int r = 0; r < 4; ++r)
        C[(rA + 16*i + quad*4 + r) * (size_t)N + rW + 16*j + l] = (__bf16)(acc[i][j][r] + bv);
  }
}

// ---------------- grid barrier: 16 counters 128B apart, write-through publication ----
__device__ __forceinline__ void grid_barrier16(unsigned* bars, int my_ctr, unsigned target){
  __syncthreads();   // drains this block's vmem stores (incl. write-through h stores)
  if (threadIdx.x < NCTR){
    if ((int)threadIdx.x == my_ctr)
      __hip_atomic_fetch_add(bars + my_ctr * CTR_STRIDE, 1u,
                             __ATOMIC_RELAXED, __HIP_MEMORY_SCOPE_AGENT);
    while (__hip_atomic_load(bars + threadIdx.x * CTR_STRIDE,
                             __ATOMIC_RELAXED, __HIP_MEMORY_SCOPE_AGENT) < target)
      __builtin_amdgcn_s_sleep(2);
  }
  __syncthreads();
}

// agent-coherent 16B load (bypasses possibly-stale per-XCD L2)
__device__ __forceinline__ bhalf8 load_coherent16(const __bf16* p){
  union { unsigned long long q[2]; bhalf8 v; } u;
  u.q[0] = __hip_atomic_load((const unsigned long long*)p,     __ATOMIC_RELAXED, __HIP_MEMORY_SCOPE_AGENT);
  u.q[1] = __hip_atomic_load((const unsigned long long*)p + 1, __ATOMIC_RELAXED, __HIP_MEMORY_SCOPE_AGENT);
  return u.v;
}

// 3-gate MFMA accumulation over LEN columns (LEN % 32 == 0)
template<int LEN>
__device__ __forceinline__ void gemm3(const __bf16* __restrict__ a,
    const __bf16* __restrict__ w0, const __bf16* __restrict__ w1,
    const __bf16* __restrict__ w2, int quad,
    floatx4& a0, floatx4& a1, floatx4& a2)
{
#pragma unroll
  for (int ks = 0; ks < LEN/32; ++ks){
    bhalf8 av = load_coherent16(a + ks*32 + quad*8);
    bhalf8 v0 = *(const bhalf8*)(w0 + ks*32 + quad*8);
    bhalf8 v1 = *(const bhalf8*)(w1 + ks*32 + quad*8);
    bhalf8 v2 = *(const bhalf8*)(w2 + ks*32 + quad*8);
    a0 = __builtin_amdgcn_mfma_f32_16x16x32_bf16(av, v0, a0, 0, 0, 0);
    a1 = __builtin_amdgcn_mfma_f32_16x16x32_bf16(av, v1, a1, 0, 0, 0);
    a2 = __builtin_amdgcn_mfma_f32_16x16x32_bf16(av, v2, a2, 0, 0, 0);
  }
}

// ---------------- fused 4-layer wavefront scan ----------------
struct ScanArgs {
  const __bf16* xg0;        // [B*T][1536] L0 input gates, b_ih baked in
  const __bf16* w[4];       // L0: Whh [1536][512]; L>=1: [Wih|Whh] [3H][INDIM+H]
  const float*  bih[4];
  const float*  bhh[4];
  __bf16* h[4][2];          // per-layer recurrent double buffer [32][H]
  __bf16* Y;                // [B*T][1024] final (L3 output)
  unsigned* bar;            // NCTR counters, CTR_STRIDE apart
};

// Layer L at global step s processes its local timestep t = s - L.
// Reads: recurrent h[L][t&1] (holds h_L[t-1]); input h[L-1][(t&1)^1] (holds h_{L-1}[t]).
// Writes: h[L][(t+1)&1] <- h_L[t].  Wave roles: m = batch half, kh = 0:input / 1:recurrent.
template<int L, int INDIM, int H>
__device__ void run_layer(const ScanArgs& A, int lb, int nlb)
{
  __shared__ float part[2*3*2*16*17];  // [kh][gate][m][row16][col16 pad17]
  __shared__ float hown[32*17];        // private fp32 h for this block's 16 units
  const int tid = threadIdx.x, wave = tid >> 6, lane = tid & 63;
  const int quad = lane >> 4, l = lane & 15;
  const int m = wave & 1, kh = wave >> 1;
  const int swz = (lb & 7) * (nlb >> 3) + (lb >> 3);   // XCD-contiguous unit mapping
  const int u0 = swz * 16;
  const int my_ctr = (int)(blockIdx.x & (NCTR - 1));
  const unsigned per_ctr = NBLK / NCTR;                // 12 arrivals per counter per epoch

  for (int i = tid; i < 32*16; i += 256){ int b = i >> 4, u = i & 15; hown[b*17 + u] = 0.0f; }
  // publish h[-1] = 0 (parity 0) write-through
  for (int i = tid; i < 32*8; i += 256){
    int b = i >> 3, d = i & 7;
    __hip_atomic_store((unsigned*)(A.h[L][0] + (size_t)b*H + u0) + d, 0u,
                       __ATOMIC_RELAXED, __HIP_MEMORY_SCOPE_AGENT);
  }
  // biases: r/z gates take bih+bhh summed; n gate keeps input-side (bih) and
  // recurrent-side (bhh) separate because r multiplies only the recurrent part.
  const float bb0 = A.bhh[L][0*H + u0 + l] + ((L > 0) ? A.bih[L][0*H + u0 + l] : 0.0f);
  const float bb1 = A.bhh[L][1*H + u0 + l] + ((L > 0) ? A.bih[L][1*H + u0 + l] : 0.0f);
  const float bxn = (L > 0) ? A.bih[L][2*H + u0 + l] : 0.0f;
  const float bhn = A.bhh[L][2*H + u0 + l];

  constexpr int WS = (L == 0) ? H : (INDIM + H);       // weight row stride
  const int wcb = (L == 0) ? kh*(H/2) : (kh ? INDIM : 0);
  const __bf16* wp0 = A.w[L] + (size_t)(0*H + u0 + l)*WS + wcb;
  const __bf16* wp1 = A.w[L] + (size_t)(1*H + u0 + l)*WS + wcb;
  const __bf16* wp2 = A.w[L] + (size_t)(2*H + u0 + l)*WS + wcb;

  const int arow = 16*m + l;
  const __bf16* rec0 = A.h[L][0] + (size_t)arow*H + ((L == 0) ? kh*(H/2) : 0);
  const __bf16* rec1 = A.h[L][1] + (size_t)arow*H + ((L == 0) ? kh*(H/2) : 0);
  constexpr int LP = (L > 0) ? L - 1 : 0;
  const __bf16* in0 = A.h[LP][0] + (size_t)arow*INDIM;
  const __bf16* in1 = A.h[LP][1] + (size_t)arow*INDIM;

  const int b0g = 16*m + quad*4 + 2*kh;   // gating batch-row base

  __bf16 xq[3][2];
  if constexpr (L == 0){
#pragma unroll
    for (int g = 0; g < 3; ++g)
#pragma unroll
      for (int r2 = 0; r2 < 2; ++r2)
        xq[g][r2] = A.xg0[((size_t)(b0g + r2)*T_ + 0)*(size_t)(3*H) + (size_t)g*H + u0 + l];
  }

  grid_barrier16(A.bar, my_ctr, per_ctr * 1u);   // epoch 1: zeros visible everywhere

  for (int s = 0; s < T_ + 3; ++s){
    const int t = s - L;
    if (0 <= t && t < T_){
      const int pr = t & 1;
      floatx4 a0 = {0.f,0.f,0.f,0.f}, a1 = a0, a2 = a0;
      if constexpr (L == 0){
        gemm3<H/2>(pr ? rec1 : rec0, wp0, wp1, wp2, quad, a0, a1, a2);
      } else {
        if (kh == 0) gemm3<INDIM>(pr ? in0 : in1, wp0, wp1, wp2, quad, a0, a1, a2);
        else         gemm3<H>(pr ? rec1 : rec0, wp0, wp1, wp2, quad, a0, a1, a2);
      }
      const int sb = (kh*6 + m)*272;
#pragma unroll
      for (int r = 0; r < 4; ++r){
        part[sb +        (quad*4+r)*17 + l] = a0[r];
        part[sb + 544  + (quad*4+r)*17 + l] = a1[r];
        part[sb + 1088 + (quad*4+r)*17 + l] = a2[r];
      }
      __syncthreads();
#pragma unroll
      for (int r2 = 0; r2 < 2; ++r2){
        const int row = quad*4 + 2*kh + r2;
        const int bb  = 16*m + row;
        const float pr_a = part[(0+m)*272 + row*17 + l], pr_b = part[(6+m)*272  + row*17 + l];
        const float pz_a = part[(2+m)*272 + row*17 + l], pz_b = part[(8+m)*272  + row*17 + l];
        const float pn_a = part[(4+m)*272 + row*17 + l], pn_b = part[(10+m)*272 + row*17 + l];
        float rg, zg, ng;
        if constexpr (L == 0){
          const float xr = (float)xq[0][r2], xz = (float)xq[1][r2], xn = (float)xq[2][r2];
          rg = sigm_f(xr + pr_a + pr_b + bb0);
          zg = sigm_f(xz + pz_a + pz_b + bb1);
          ng = tanh_f(xn + rg*(pn_a + pn_b + bhn));
        } else {
          rg = sigm_f(pr_a + pr_b + bb0);
          zg = sigm_f(pz_a + pz_b + bb1);
          ng = tanh_f(pn_a + bxn + rg*(pn_b + bhn));   // input side NOT scaled by r
        }
        const float hp = hown[bb*17 + l];
        const float hnew = (1.0f - zg)*ng + zg*hp;
        hown[bb*17 + l] = hnew;
        const __bf16 hb16 = (__bf16)hnew;
        const unsigned mybits = (unsigned)__builtin_bit_cast(unsigned short, hb16);
        const unsigned other  = (unsigned)__shfl_xor((int)mybits, 1);
        if ((l & 1) == 0){
          const unsigned packed = mybits | (other << 16);
          __bf16* hd = pr ? A.h[L][0] : A.h[L][1];   // write parity (t+1)&1
          __hip_atomic_store((unsigned*)(hd + (size_t)bb*H + u0 + l), packed,
                             __ATOMIC_RELAXED, __HIP_MEMORY_SCOPE_AGENT);
          if constexpr (L == 3)
            __builtin_nontemporal_store(packed, (unsigned*)(A.Y + ((size_t)bb*T_ + t)*H + u0 + l));
        }
      }
      if constexpr (L == 0){
        if (t + 1 < T_){
#pragma unroll
          for (int g = 0; g < 3; ++g)
#pragma unroll
            for (int r2 = 0; r2 < 2; ++r2)
              xq[g][r2] = A.xg0[((size_t)(b0g + r2)*T_ + (t+1))*(size_t)(3*H) + (size_t)g*H + u0 + l];
        }
      }
    }
    if (s + 1 < T_ + 3)
      grid_barrier16(A.bar, my_ctr, per_ctr * (unsigned)(s + 2));
  }
}

__global__ __launch_bounds__(256) void k_scan4(ScanArgs A)
{
  const int bid = blockIdx.x;
  if      (bid < 32)  run_layer<0,    0,  512>(A, bid,       32);
  else if (bid < 64)  run_layer<1,  512,  512>(A, bid - 32,  32);
  else if (bid < 128) run_layer<2,  512, 1024>(A, bid - 64,  64);
  else                run_layer<3, 1024, 1024>(A, bid - 128, 64);
}

// ---------------- launch ----------------
extern "C" void kernel_launch(void* const* d_in, const int* in_sizes, int n_in,
                              void* d_out, int out_size, void* d_ws, size_t ws_size,
                              hipStream_t stream) {
  (void)in_sizes; (void)n_in; (void)out_size; (void)ws_size;
  const float* x = (const float*)d_in[0];
  const float* wih[4] = {(const float*)d_in[1], (const float*)d_in[5], (const float*)d_in[9],  (const float*)d_in[13]};
  const float* whh[4] = {(const float*)d_in[2], (const float*)d_in[6], (const float*)d_in[10], (const float*)d_in[14]};
  const float* bih[4] = {(const float*)d_in[3], (const float*)d_in[7], (const float*)d_in[11], (const float*)d_in[15]};
  const float* bhh[4] = {(const float*)d_in[4], (const float*)d_in[8], (const float*)d_in[12], (const float*)d_in[16]};
  float* out = (float*)d_out;

  char* ws = (char*)d_ws;
  size_t off = 0;
  auto take = [&](size_t bytes)->char* {
    char* p = ws + off; off = (off + bytes + 255) & ~(size_t)255; return p;
  };

  unsigned* bars = (unsigned*)take((size_t)NCTR * CTR_STRIDE * sizeof(unsigned));
  __bf16* wihb0 = (__bf16*)take((size_t)1536 *  256 * 2);   // L0 Wih bf16
  __bf16* whhb0 = (__bf16*)take((size_t)1536 *  512 * 2);   // L0 Whh
  __bf16* WC1   = (__bf16*)take((size_t)1536 * 1024 * 2);   // L1 [Wih|Whh]
  __bf16* WC2   = (__bf16*)take((size_t)3072 * 1536 * 2);   // L2 [Wih|Whh]
  __bf16* WC3   = (__bf16*)take((size_t)3072 * 2048 * 2);   // L3 [Wih|Whh]
  __bf16* XG0   = (__bf16*)take((size_t)B_*T_*1536*2);      // 201 MB, L0 input gates
  __bf16* Yb    = (__bf16*)take((size_t)B_*T_*1024*2);      // 134 MB, final output bf16
  __bf16* hbuf[4][2];
  const int HH[4] = {512, 512, 1024, 1024};
  for (int i = 0; i < 4; ++i)
    for (int p = 0; p < 2; ++p)
      hbuf[i][p] = (__bf16*)take((size_t)B_ * HH[i] * 2);
  __bf16* X0 = Yb;  // alias: X0 consumed by k_gemm before the scan writes Yb

  k_init<<<2, 256, 0, stream>>>(bars);
  { const int n = 1536*256; k_cvt<<<(n+255)/256, 256, 0, stream>>>(wih[0], wihb0, n); }
  { const int n = 1536*512; k_cvt<<<(n+255)/256, 256, 0, stream>>>(whh[0], whhb0, n); }
  // pack [Wih | Whh] for L1..L3
  { int n=1536*512;  k_pack<<<(n+255)/256,256,0,stream>>>(wih[1], WC1, 1536,  512, 1024,    0); }
  { int n=1536*512;  k_pack<<<(n+255)/256,256,0,stream>>>(whh[1], WC1, 1536,  512, 1024,  512); }
  { int n=3072*512;  k_pack<<<(n+255)/256,256,0,stream>>>(wih[2], WC2, 3072,  512, 1536,    0); }
  { int n=3072*1024; k_pack<<<(n+255)/256,256,0,stream>>>(whh[2], WC2, 3072, 1024, 1536,  512); }
  { int n=3072*1024; k_pack<<<(n+255)/256,256,0,stream>>>(wih[3], WC3, 3072, 1024, 2048,    0); }
  { int n=3072*1024; k_pack<<<(n+255)/256,256,0,stream>>>(whh[3], WC3, 3072, 1024, 2048, 1024); }

  // x [B][256][T] -> X0 [B][T][256] bf16
  k_transpose<float, __bf16><<<dim3(T_/32, 256/32, B_), dim3(32, 8), 0, stream>>>(x, X0, 256, T_);

  // L0 input gates: XG0 = X0 * Wih0^T + bih0  (M=B*T, N=1536, K=256)
  const int M = B_ * T_;
  k_gemm<<<dim3(1536/128, M/128), 256, 0, stream>>>(X0, wihb0, bih[0], XG0, M, 1536, 256);

  ScanArgs A;
  A.xg0 = XG0;
  A.w[0] = whhb0; A.w[1] = WC1; A.w[2] = WC2; A.w[3] = WC3;
  for (int i = 0; i < 4; ++i){ A.bih[i] = bih[i]; A.bhh[i] = bhh[i]; }
  for (int i = 0; i < 4; ++i) for (int p = 0; p < 2; ++p) A.h[i][p] = hbuf[i][p];
  A.Y = Yb; A.bar = bars;
  k_scan4<<<NBLK, 256, 0, stream>>>(A);

  // Yb [B][T][1024] -> out [B][1024][T] fp32
  k_transpose<__bf16, float><<<dim3(1024/32, T_/32, B_), dim3(32, 8), 0, stream>>>(Yb, out, T_, 1024);
}